// Round 1
// 225.017 us; speedup vs baseline: 1.0603x; 1.0603x over previous
//
#include <hip/hip_runtime.h>

#define VOCAB   8
#define HIDDEN  768
#define DINUC   192
#define CONCAT  960
#define NDID    17               // 16 dinuc ids + 1 "no dinuc" (last position)
#define NROWS   (VOCAB * NDID)   // 136 distinct output rows
#define SEQ     2048
#define BATCH   32
#define LN_EPS  1e-12f

typedef float v4f __attribute__((ext_vector_type(4)));  // native vec for nontemporal

// ---------------------------------------------------------------------------
// K1: one WAVE per dot product (coalesced W reads + 6-step shuffle reduce).
//   TD[r][o], r in [0,8):   tok[r](768) . W[o][0:768]
//   TD[r][o], r in [8,24):  din[r-8](192) . W[o][768:960]
// 24*768 = 18432 waves = 4608 blocks x 256 thr. W row read as 64 lanes x
// float4 contiguous (1 KB/inst). ~28 MB of mostly-L2 traffic; a few µs.
// ---------------------------------------------------------------------------
__global__ __launch_bounds__(256) void k_td(
    const float* __restrict__ tok, const float* __restrict__ din,
    const float* __restrict__ W, float* __restrict__ TD) {
    int w    = (blockIdx.x * 256 + threadIdx.x) >> 6;   // wave id: 0..18431
    int lane = threadIdx.x & 63;
    int r    = w / HIDDEN;                              // 0..23 (wave-uniform)
    int o    = w - r * HIDDEN;                          // 0..767

    float acc = 0.f;
    if (r < VOCAB) {
        const float4* e4 = (const float4*)(tok + r * HIDDEN);
        const float4* w4 = (const float4*)(W + (size_t)o * CONCAT);
        #pragma unroll
        for (int k = 0; k < 3; ++k) {                   // 3 * 64 * 4 = 768
            float4 a = w4[k * 64 + lane];
            float4 b = e4[k * 64 + lane];
            acc += a.x * b.x + a.y * b.y + a.z * b.z + a.w * b.w;
        }
    } else {
        if (lane < 48) {                                // 48 * 4 = 192
            const float4* e4 = (const float4*)(din + (r - VOCAB) * DINUC);
            const float4* w4 = (const float4*)(W + (size_t)o * CONCAT + HIDDEN);
            float4 a = w4[lane];
            float4 b = e4[lane];
            acc = a.x * b.x + a.y * b.y + a.z * b.z + a.w * b.w;
        }
    }
    #pragma unroll
    for (int m = 32; m; m >>= 1) acc += __shfl_xor(acc, m, 64);
    if (lane == 0) TD[w] = acc;
}

// ---------------------------------------------------------------------------
// K2: table[row=(id*17+did)][o] = LN( T[id][o] + (did<16 ? D[did][o] : 0) + b[o] )
// One block (256 thr = 4 waves) per row; each thread owns 3 outputs.
// ---------------------------------------------------------------------------
__device__ inline float block_reduce_sum(float s, float* red) {
    int lane = threadIdx.x & 63;
    int wave = threadIdx.x >> 6;
    #pragma unroll
    for (int off = 32; off; off >>= 1) s += __shfl_down(s, off, 64);
    if (lane == 0) red[wave] = s;
    __syncthreads();
    float tot = red[0] + red[1] + red[2] + red[3];
    __syncthreads();
    return tot;
}

__global__ __launch_bounds__(256) void k_table(
    const float* __restrict__ TD, const float* __restrict__ bias,
    const float* __restrict__ gamma, const float* __restrict__ beta,
    float* __restrict__ table) {
    int row = blockIdx.x;          // 0..135
    int id  = row / NDID;
    int did = row - id * NDID;
    const float* T = TD + id * HIDDEN;
    const float* D = TD + (VOCAB + did) * HIDDEN;
    bool hasd = (did < 16);

    __shared__ float red[4];
    int tid = threadIdx.x;

    float v[3];
    float s = 0.f;
    #pragma unroll
    for (int k = 0; k < 3; ++k) {
        int o = tid + k * 256;
        float x = T[o] + bias[o];
        if (hasd) x += D[o];
        v[k] = x;
        s += x;
    }
    float mu = block_reduce_sum(s, red) * (1.f / HIDDEN);

    float sq = 0.f;
    #pragma unroll
    for (int k = 0; k < 3; ++k) {
        float d = v[k] - mu;
        sq += d * d;
    }
    float var = block_reduce_sum(sq, red) * (1.f / HIDDEN);
    float rstd = rsqrtf(var + LN_EPS);

    #pragma unroll
    for (int k = 0; k < 3; ++k) {
        int o = tid + k * 256;
        table[row * HIDDEN + o] = (v[k] - mu) * rstd * gamma[o] + beta[o];
    }
}

// ---------------------------------------------------------------------------
// K3: broadcast. out[b,s,:] = table[id*17+did].
// NEW STRUCTURE: one WAVE per output row. 64 lanes x 3 float4 = 3 KB payload
// per wave behind a SINGLE ids->table dependent chain (3x amortization vs the
// old 1-float4-per-thread layout), 3 independent load->store pairs per thread
// (ILP), and 256-thr blocks -> up to 8 blocks = 32 waves/CU residency (the
// old 768-thr blocks capped at 2 blocks = 24 waves/CU). Old version delivered
// ~24 B/cy/CU — exactly at the 25.7 B/cy/CU write roofline with no margin;
// this gives ~4.7x margin so the NT store stream becomes the limiter.
// Non-temporal stores: pure 201 MB write stream, don't allocate in L2.
// ---------------------------------------------------------------------------
__global__ __launch_bounds__(256) void k_bcast(
    const int* __restrict__ ids,
    const float* __restrict__ table,
    v4f* __restrict__ out) {
    int row  = (blockIdx.x * 256 + threadIdx.x) >> 6;   // 0 .. 65535 (= b*SEQ + s)
    int lane = threadIdx.x & 63;
    int s    = row & (SEQ - 1);
    int a    = ids[row];                                // wave-uniform (L1 broadcast)
    int did;
    if (s == SEQ - 1) {
        did = 16;                                       // padded position: no dinuc
    } else {
        int b = ids[row + 1];
        bool valid = (a >= 4) & (a <= 7) & (b >= 4) & (b <= 7);
        did = valid ? ((a - 4) * 4 + (b - 4)) : 0;
    }
    const v4f* src = (const v4f*)(table + (a * NDID + did) * HIDDEN);
    v4f* dst = out + (size_t)row * (HIDDEN / 4);

    // 3 independent load->store pairs; loads issue back-to-back, stores drain
    // as each returns. 192 v4f = full row.
    v4f v0 = src[lane];
    v4f v1 = src[lane + 64];
    v4f v2 = src[lane + 128];
    __builtin_nontemporal_store(v0, dst + lane);
    __builtin_nontemporal_store(v1, dst + lane + 64);
    __builtin_nontemporal_store(v2, dst + lane + 128);
}

// ---------------------------------------------------------------------------
extern "C" void kernel_launch(void* const* d_in, const int* in_sizes, int n_in,
                              void* d_out, int out_size, void* d_ws, size_t ws_size,
                              hipStream_t stream) {
    const int*   ids   = (const int*)d_in[0];
    const float* tok   = (const float*)d_in[1];
    const float* din   = (const float*)d_in[2];
    const float* W     = (const float*)d_in[3];
    const float* bias  = (const float*)d_in[4];
    const float* gamma = (const float*)d_in[5];
    const float* beta  = (const float*)d_in[6];

    float* table = (float*)d_ws;                 // 136*768 floats = 417792 B
    float* TD    = table + NROWS * HIDDEN;       //  24*768 floats =  73728 B

    k_td   <<<(24 * HIDDEN) / 4, 256, 0, stream>>>(tok, din, W, TD);
    k_table<<<NROWS, 256, 0, stream>>>(TD, bias, gamma, beta, table);
    // one wave per row: 65536 rows * 64 lanes / 256 thr = 16384 blocks
    k_bcast<<<(BATCH * SEQ) / 4, 256, 0, stream>>>(ids, table, (v4f*)d_out);
}

// Round 2
// 222.205 us; speedup vs baseline: 1.0737x; 1.0127x over previous
//
#include <hip/hip_runtime.h>

#define VOCAB   8
#define HIDDEN  768
#define DINUC   192
#define CONCAT  960
#define NDID    17               // 16 dinuc ids + 1 "no dinuc" (last position)
#define NROWS   (VOCAB * NDID)   // 136 distinct output rows
#define SEQ     2048
#define BATCH   32
#define LN_EPS  1e-12f

typedef float v4f __attribute__((ext_vector_type(4)));  // native vec for nontemporal

// ---------------------------------------------------------------------------
// K1: one WAVE per dot product (coalesced W reads + 6-step shuffle reduce).
//   TD[r][o], r in [0,8):   tok[r](768) . W[o][0:768]
//   TD[r][o], r in [8,24):  din[r-8](192) . W[o][768:960]
// 24*768 = 18432 waves = 4608 blocks x 256 thr. W row read as 64 lanes x
// float4 contiguous (1 KB/inst). ~28 MB of mostly-L2 traffic; a few µs.
// ---------------------------------------------------------------------------
__global__ __launch_bounds__(256) void k_td(
    const float* __restrict__ tok, const float* __restrict__ din,
    const float* __restrict__ W, float* __restrict__ TD) {
    int w    = (blockIdx.x * 256 + threadIdx.x) >> 6;   // wave id: 0..18431
    int lane = threadIdx.x & 63;
    int r    = w / HIDDEN;                              // 0..23 (wave-uniform)
    int o    = w - r * HIDDEN;                          // 0..767

    float acc = 0.f;
    if (r < VOCAB) {
        const float4* e4 = (const float4*)(tok + r * HIDDEN);
        const float4* w4 = (const float4*)(W + (size_t)o * CONCAT);
        #pragma unroll
        for (int k = 0; k < 3; ++k) {                   // 3 * 64 * 4 = 768
            float4 a = w4[k * 64 + lane];
            float4 b = e4[k * 64 + lane];
            acc += a.x * b.x + a.y * b.y + a.z * b.z + a.w * b.w;
        }
    } else {
        if (lane < 48) {                                // 48 * 4 = 192
            const float4* e4 = (const float4*)(din + (r - VOCAB) * DINUC);
            const float4* w4 = (const float4*)(W + (size_t)o * CONCAT + HIDDEN);
            float4 a = w4[lane];
            float4 b = e4[lane];
            acc = a.x * b.x + a.y * b.y + a.z * b.z + a.w * b.w;
        }
    }
    #pragma unroll
    for (int m = 32; m; m >>= 1) acc += __shfl_xor(acc, m, 64);
    if (lane == 0) TD[w] = acc;
}

// ---------------------------------------------------------------------------
// K2: table[row=(id*17+did)][o] = LN( T[id][o] + (did<16 ? D[did][o] : 0) + b[o] )
// One block (256 thr = 4 waves) per row; each thread owns 3 outputs.
// ---------------------------------------------------------------------------
__device__ inline float block_reduce_sum(float s, float* red) {
    int lane = threadIdx.x & 63;
    int wave = threadIdx.x >> 6;
    #pragma unroll
    for (int off = 32; off; off >>= 1) s += __shfl_down(s, off, 64);
    if (lane == 0) red[wave] = s;
    __syncthreads();
    float tot = red[0] + red[1] + red[2] + red[3];
    __syncthreads();
    return tot;
}

__global__ __launch_bounds__(256) void k_table(
    const float* __restrict__ TD, const float* __restrict__ bias,
    const float* __restrict__ gamma, const float* __restrict__ beta,
    float* __restrict__ table) {
    int row = blockIdx.x;          // 0..135
    int id  = row / NDID;
    int did = row - id * NDID;
    const float* T = TD + id * HIDDEN;
    const float* D = TD + (VOCAB + did) * HIDDEN;
    bool hasd = (did < 16);

    __shared__ float red[4];
    int tid = threadIdx.x;

    float v[3];
    float s = 0.f;
    #pragma unroll
    for (int k = 0; k < 3; ++k) {
        int o = tid + k * 256;
        float x = T[o] + bias[o];
        if (hasd) x += D[o];
        v[k] = x;
        s += x;
    }
    float mu = block_reduce_sum(s, red) * (1.f / HIDDEN);

    float sq = 0.f;
    #pragma unroll
    for (int k = 0; k < 3; ++k) {
        float d = v[k] - mu;
        sq += d * d;
    }
    float var = block_reduce_sum(sq, red) * (1.f / HIDDEN);
    float rstd = rsqrtf(var + LN_EPS);

    #pragma unroll
    for (int k = 0; k < 3; ++k) {
        int o = tid + k * 256;
        table[row * HIDDEN + o] = (v[k] - mu) * rstd * gamma[o] + beta[o];
    }
}

// ---------------------------------------------------------------------------
// K3: broadcast. out[b,s,:] = table[id*17+did].
// ONE WAVE PER ROW-PAIR: 6 KB payload per ids->table dependent chain (2x the
// previous version), 6 independent load->store pairs of ILP per thread, and
// half as many ids-load chains. Even row of the pair can never be the last
// position of a sequence (SEQ-1 is odd), so it needs no boundary branch, and
// its two ids come from one aligned int2 load. The pair's second row needs at
// most one extra ids load (wave-uniform branch). 8192 blocks x 256 thr.
// Non-temporal stores: pure 201 MB write stream, don't allocate in L2.
// ---------------------------------------------------------------------------
__global__ __launch_bounds__(256) void k_bcast(
    const int* __restrict__ ids,
    const float* __restrict__ table,
    v4f* __restrict__ out) {
    int w    = (blockIdx.x * 256 + threadIdx.x) >> 6;   // pair id: 0..32767
    int lane = threadIdx.x & 63;
    int r0   = w << 1;                                  // even row
    int s0   = r0 & (SEQ - 1);                          // even => never SEQ-1

    int2 p01 = *(const int2*)(ids + r0);                // ids[r0], ids[r0+1]
    int a0 = p01.x, a1 = p01.y;

    // row r0: dinuc always from (a0, a1)
    bool v0  = (a0 >= 4) & (a0 <= 7) & (a1 >= 4) & (a1 <= 7);
    int did0 = v0 ? ((a0 - 4) * 4 + (a1 - 4)) : 0;

    // row r1 = r0+1: last position iff s0+1 == SEQ-1 (wave-uniform branch)
    int did1;
    if (s0 + 1 == SEQ - 1) {
        did1 = 16;
    } else {
        int b1   = ids[r0 + 2];                         // in-bounds: same sequence
        bool v1  = (a1 >= 4) & (a1 <= 7) & (b1 >= 4) & (b1 <= 7);
        did1 = v1 ? ((a1 - 4) * 4 + (b1 - 4)) : 0;
    }

    const v4f* src0 = (const v4f*)(table + (a0 * NDID + did0) * HIDDEN);
    const v4f* src1 = (const v4f*)(table + (a1 * NDID + did1) * HIDDEN);
    v4f* dst = out + (size_t)r0 * (HIDDEN / 4);

    // 6 independent loads issue back-to-back; stores drain as each returns.
    v4f x0 = src0[lane];
    v4f x1 = src0[lane + 64];
    v4f x2 = src0[lane + 128];
    v4f y0 = src1[lane];
    v4f y1 = src1[lane + 64];
    v4f y2 = src1[lane + 128];
    __builtin_nontemporal_store(x0, dst + lane);
    __builtin_nontemporal_store(x1, dst + lane + 64);
    __builtin_nontemporal_store(x2, dst + lane + 128);
    __builtin_nontemporal_store(y0, dst + 192 + lane);
    __builtin_nontemporal_store(y1, dst + 192 + lane + 64);
    __builtin_nontemporal_store(y2, dst + 192 + lane + 128);
}

// ---------------------------------------------------------------------------
extern "C" void kernel_launch(void* const* d_in, const int* in_sizes, int n_in,
                              void* d_out, int out_size, void* d_ws, size_t ws_size,
                              hipStream_t stream) {
    const int*   ids   = (const int*)d_in[0];
    const float* tok   = (const float*)d_in[1];
    const float* din   = (const float*)d_in[2];
    const float* W     = (const float*)d_in[3];
    const float* bias  = (const float*)d_in[4];
    const float* gamma = (const float*)d_in[5];
    const float* beta  = (const float*)d_in[6];

    float* table = (float*)d_ws;                 // 136*768 floats = 417792 B
    float* TD    = table + NROWS * HIDDEN;       //  24*768 floats =  73728 B

    k_td   <<<(24 * HIDDEN) / 4, 256, 0, stream>>>(tok, din, W, TD);
    k_table<<<NROWS, 256, 0, stream>>>(TD, bias, gamma, beta, table);
    // one wave per row-pair: 32768 pairs * 64 lanes / 256 thr = 8192 blocks
    k_bcast<<<(BATCH * SEQ) / 8, 256, 0, stream>>>(ids, table, (v4f*)d_out);
}